// Round 12
// baseline (111.361 us; speedup 1.0000x reference)
//
#include <hip/hip_runtime.h>

#define H 1024
#define LEN 8192
#define V 50000
#define NTILE 12500   // k_out: V/4 rows per tile
#define NBO 500       // k_out blocks: 12500/500 = exactly 25 tiles each
#define CHUNK 8
#define NCH (LEN / CHUNK)   // 1024 chunks per batch

__device__ __forceinline__ float dot4(float4 a, float4 b) {
    return a.x * b.x + a.y * b.y + a.z * b.z + a.w * b.w;
}

__device__ __forceinline__ void gld_lds16(const float* g, float* l) {
    __builtin_amdgcn_global_load_lds(
        (const __attribute__((address_space(1))) void*)g,
        (__attribute__((address_space(3))) void*)l, 16, 0, 0);
}

// ---------------------------------------------------------------------------
// K1: u[h] = sum_k v[k]*attn_w[k*2048+1024+h].  grid 64 x 256 (R5 body).
// Must run before k_fuse (ctx blocks read U).
// ---------------------------------------------------------------------------
__global__ void k_u(const float* __restrict__ attn_w,
                    const float* __restrict__ v,
                    float* __restrict__ u) {
    __shared__ float red[16][16];
    int bid = blockIdx.x;
    int t   = threadIdx.x;
    int kg  = t >> 4;            // 0..15
    int hi  = t & 15;            // 0..15
    int h   = bid * 16 + hi;
    float acc = 0.f;
#pragma unroll 8
    for (int i = 0; i < 64; ++i) {
        int k = kg * 64 + i;
        acc += v[k] * attn_w[(long)k * (2 * H) + H + h];
    }
    red[kg][hi] = acc;
    __syncthreads();
    if (t < 16) {
        float s = 0.f;
#pragma unroll
        for (int g = 0; g < 16; ++g) s += red[g][t];
        u[bid * 16 + t] = s;
    }
}

// ---------------------------------------------------------------------------
// K2: fused ctx + GRU + emb. Uniform one-shot blocks, interleaved 2:1 so the
// latency-bound GRU blocks ride under the BW-bound enc stream:
//   bid<3072:  r=bid%3: r<2 -> ctx chunk (q*2+r);  r==2 -> GRU hh=q
//   bid>=3072: embedding gather (8 blocks)
// LDS 32.8 KB -> 4 blocks/CU. grid 3080 x 256.
// ---------------------------------------------------------------------------
__global__ void __launch_bounds__(256)
k_fuse(const float* __restrict__ enc,
       const float* __restrict__ u,
       float* __restrict__ pvec,
       float* __restrict__ marr,
       float* __restrict__ sarr,
       const int* __restrict__ ids,
       const float* __restrict__ emb,
       const float* __restrict__ lctx,
       const float* __restrict__ lhid,
       const float* __restrict__ w_ih,
       const float* __restrict__ w_hh,
       const float* __restrict__ b_ih,
       const float* __restrict__ b_hh,
       float* __restrict__ o_hidden,
       float* __restrict__ o_rnn,
       float* __restrict__ o_embedded) {
    __shared__ float smem[CHUNK * H + 8];   // 32.8 KB (ctx: erow+elds; GRU: scratch)
    int t    = threadIdx.x;
    int lane = t & 63;
    int wv   = t >> 6;
    int bid  = blockIdx.x;

    if (bid >= 3072) {
        int idx = (bid - 3072) * 256 + t;   // 0..2047
        int b = idx >> 10, h = idx & 1023;
        o_embedded[idx] = emb[(long)ids[b] * H + h];
        return;
    }

    int r3 = bid % 3;
    int q3 = bid / 3;           // 0..1023

    if (r3 == 2) {
        // ---- GRU cell for output element hh (R5-proven body) ----
        int hh = q3;
        float* glds = smem;     // 48 floats scratch
        int kb = t * 8;
        float4 x0a, x0b, x1a, x1b;
        if (kb < H) {
            const float* p0 = emb + (long)ids[0] * H + kb;
            const float* p1 = emb + (long)ids[1] * H + kb;
            x0a = *(const float4*)p0;  x0b = *(const float4*)(p0 + 4);
            x1a = *(const float4*)p1;  x1b = *(const float4*)(p1 + 4);
        } else {
            const float* p0 = lctx + (kb - H);
            const float* p1 = lctx + H + (kb - H);
            x0a = *(const float4*)p0;  x0b = *(const float4*)(p0 + 4);
            x1a = *(const float4*)p1;  x1b = *(const float4*)(p1 + 4);
        }
        int kb2 = t * 4;
        float4 h0 = *(const float4*)(lhid + kb2);
        float4 h1 = *(const float4*)(lhid + H + kb2);

        for (int g = 0; g < 3; ++g) {
            const float* wi = w_ih + ((long)g * H + hh) * (2 * H) + kb;
            const float* wh = w_hh + ((long)g * H + hh) * H + kb2;
            float4 wa = *(const float4*)wi;
            float4 wb = *(const float4*)(wi + 4);
            float4 wc = *(const float4*)wh;
            float a0 = dot4(wa, x0a) + dot4(wb, x0b);
            float a1 = dot4(wa, x1a) + dot4(wb, x1b);
            float c0 = dot4(wc, h0);
            float c1 = dot4(wc, h1);
            for (int off = 32; off; off >>= 1) {
                a0 += __shfl_down(a0, off, 64);
                a1 += __shfl_down(a1, off, 64);
                c0 += __shfl_down(c0, off, 64);
                c1 += __shfl_down(c1, off, 64);
            }
            if (lane == 0) {
                glds[(g * 4 + wv) * 4 + 0] = a0;
                glds[(g * 4 + wv) * 4 + 1] = a1;
                glds[(g * 4 + wv) * 4 + 2] = c0;
                glds[(g * 4 + wv) * 4 + 3] = c1;
            }
        }
        __syncthreads();
        if (t == 0) {
            float gx[3][2], gh[3][2];
            for (int g = 0; g < 3; ++g) {
                float s0 = 0, s1 = 0, s2 = 0, s3 = 0;
                for (int w = 0; w < 4; ++w) {
                    s0 += glds[(g * 4 + w) * 4 + 0];
                    s1 += glds[(g * 4 + w) * 4 + 1];
                    s2 += glds[(g * 4 + w) * 4 + 2];
                    s3 += glds[(g * 4 + w) * 4 + 3];
                }
                float bi = b_ih[g * H + hh], bh = b_hh[g * H + hh];
                gx[g][0] = s0 + bi; gx[g][1] = s1 + bi;
                gh[g][0] = s2 + bh; gh[g][1] = s3 + bh;
            }
            for (int b = 0; b < 2; ++b) {
                float r  = 1.f / (1.f + expf(-(gx[0][b] + gh[0][b])));
                float z  = 1.f / (1.f + expf(-(gx[1][b] + gh[1][b])));
                float n  = tanhf(gx[2][b] + r * gh[2][b]);
                float hp = lhid[b * H + hh];
                float hn = (1.f - z) * n + z * hp;
                o_hidden[b * H + hh] = hn;
                o_rnn[b * H + hh]    = hn;
            }
        }
        return;
    }

    // ---- flash ctx chunk (R5-proven body) ----
    int cidx = q3 * 2 + r3;             // 0..2047
    int b    = cidx >> 10;
    int ch   = cidx & 1023;
    float* erow = smem;                 // 8192 floats
    float* elds = smem + CHUNK * H;     // 8 floats

    const float* src = enc + ((long)b * LEN + (long)ch * CHUNK) * H;
#pragma unroll
    for (int i = 0; i < CHUNK; ++i)
        gld_lds16(src + i * H + t * 4, erow + i * H + t * 4);

    float4 uf[4];
#pragma unroll
    for (int c = 0; c < 4; ++c)
        uf[c] = *(const float4*)(u + c * 256 + lane * 4);

    __syncthreads();   // staging drained

#pragma unroll
    for (int rr = 0; rr < 2; ++rr) {
        int r = wv * 2 + rr;
        float acc = 0.f;
#pragma unroll
        for (int c = 0; c < 4; ++c) {
            float4 ev = *(const float4*)(erow + r * H + c * 256 + lane * 4);
            acc += dot4(ev, uf[c]);
        }
        for (int off = 32; off; off >>= 1) acc += __shfl_down(acc, off, 64);
        if (lane == 0) elds[r] = acc;
    }
    __syncthreads();

    float m = elds[0];
#pragma unroll
    for (int r = 1; r < CHUNK; ++r) m = fmaxf(m, elds[r]);
    float p[CHUNK];
    float s = 0.f;
#pragma unroll
    for (int r = 0; r < CHUNK; ++r) { p[r] = expf(elds[r] - m); s += p[r]; }

    float4 acc = {0.f, 0.f, 0.f, 0.f};
#pragma unroll
    for (int r = 0; r < CHUNK; ++r) {
        float4 ev = *(const float4*)(erow + r * H + t * 4);
        acc.x += p[r] * ev.x; acc.y += p[r] * ev.y;
        acc.z += p[r] * ev.z; acc.w += p[r] * ev.w;
    }
    *(float4*)(pvec + (long)cidx * H + t * 4) = acc;
    if (t == 0) { marr[cidx] = m; sarr[cidx] = s; }
}

// ---------------------------------------------------------------------------
// K3: flash combine — vectorized (R11-proven). 64 blocks; block = (b, 32 h's).
// ---------------------------------------------------------------------------
__global__ void __launch_bounds__(256)
k_red(const float* __restrict__ pvec,
      const float* __restrict__ marr,
      const float* __restrict__ sarr,
      float* __restrict__ out_ctx) {
    __shared__ float scale[NCH];        // 4 KB
    __shared__ float rbuf[4];
    __shared__ float4 part[32][8];      // 4 KB
    int t  = threadIdx.x;
    int b  = blockIdx.x >> 5;           // 0..1
    int h0 = (blockIdx.x & 31) * 32;
    const float* mb = marr + b * NCH;
    const float* sb = sarr + b * NCH;

    float m = -3.4e38f;
    for (int i = t; i < NCH; i += 256) m = fmaxf(m, mb[i]);
    for (int off = 32; off; off >>= 1) m = fmaxf(m, __shfl_xor(m, off, 64));
    if ((t & 63) == 0) rbuf[t >> 6] = m;
    __syncthreads();
    m = fmaxf(fmaxf(rbuf[0], rbuf[1]), fmaxf(rbuf[2], rbuf[3]));
    __syncthreads();

    float d = 0.f;
    for (int i = t; i < NCH; i += 256) {
        float sc = expf(mb[i] - m);
        scale[i] = sc;
        d += sc * sb[i];
    }
    for (int off = 32; off; off >>= 1) d += __shfl_xor(d, off, 64);
    if ((t & 63) == 0) rbuf[t >> 6] = d;
    __syncthreads();
    float inv = 1.f / (rbuf[0] + rbuf[1] + rbuf[2] + rbuf[3]);

    int hq    = t & 7;                  // 0..7
    int clane = t >> 3;                 // 0..31
    const float* pv = pvec + (long)b * NCH * H + h0 + hq * 4;
    float4 acc = {0.f, 0.f, 0.f, 0.f};
#pragma unroll
    for (int k = 0; k < 32; ++k) {
        int c = clane + 32 * k;
        float sc = scale[c];
        float4 p = *(const float4*)(pv + (long)c * H);
        acc.x += sc * p.x; acc.y += sc * p.y;
        acc.z += sc * p.z; acc.w += sc * p.w;
    }
    part[clane][hq] = acc;
    __syncthreads();
    if (t < 8) {
        float4 s4 = {0.f, 0.f, 0.f, 0.f};
#pragma unroll
        for (int c = 0; c < 32; ++c) {
            float4 p = part[c][t];
            s4.x += p.x; s4.y += p.y; s4.z += p.z; s4.w += p.w;
        }
        s4.x *= inv; s4.y *= inv; s4.z *= inv; s4.w *= inv;
        *(float4*)(out_ctx + b * H + h0 + t * 4) = s4;
    }
}

// ---------------------------------------------------------------------------
// K4: output projection (R11-proven). grid 500 x 256, 25 tiles/block.
// ---------------------------------------------------------------------------
__global__ void __launch_bounds__(256)
k_out(const float* __restrict__ ow,
      const float* __restrict__ ob,
      const float* __restrict__ hnew,
      const float* __restrict__ ctx,
      float* __restrict__ out) {
    __shared__ float cat[2][2 * H];       // 16 KB
    __shared__ float wt[2][4 * 2 * H];    // 64 KB
    int t    = threadIdx.x;
    int lane = t & 63;
    int wv   = t >> 6;

    {
        float4* c0 = (float4*)cat[0];
        float4* c1 = (float4*)cat[1];
#pragma unroll
        for (int r = 0; r < 2; ++r) {
            int idx = t + r * 256;
            int k   = idx * 4;
            if (k < H) {
                c0[idx] = *(const float4*)(hnew + k);
                c1[idx] = *(const float4*)(hnew + H + k);
            } else {
                c0[idx] = *(const float4*)(ctx + (k - H));
                c1[idx] = *(const float4*)(ctx + H + (k - H));
            }
        }
    }
    {
        const float* src = ow + (long)blockIdx.x * (4 * 2 * H);
#pragma unroll
        for (int i = 0; i < 8; ++i)
            gld_lds16(src + i * 1024 + t * 4, wt[0] + i * 1024 + t * 4);
    }
    __syncthreads();

    const float4* c0 = (const float4*)cat[0];
    const float4* c1 = (const float4*)cat[1];
    int buf = 0;
    for (int T = blockIdx.x; T < NTILE; T += NBO) {
        int Tn = T + NBO;
        if (Tn < NTILE) {
            const float* src = ow + (long)Tn * (4 * 2 * H);
            float* dst = wt[buf ^ 1];
#pragma unroll
            for (int i = 0; i < 8; ++i)
                gld_lds16(src + i * 1024 + t * 4, dst + i * 1024 + t * 4);
        }
        const float4* wr = (const float4*)(wt[buf] + wv * (2 * H));
        float a0 = 0.f, a1 = 0.f;
#pragma unroll
        for (int j = 0; j < 8; ++j) {
            float4 w = wr[lane + 64 * j];
            a0 += dot4(w, c0[lane + 64 * j]);
            a1 += dot4(w, c1[lane + 64 * j]);
        }
        for (int off = 32; off; off >>= 1) {
            a0 += __shfl_down(a0, off, 64);
            a1 += __shfl_down(a1, off, 64);
        }
        if (lane == 0) {
            long row = (long)T * 4 + wv;
            float bb = ob[row];
            out[row]     = a0 + bb;
            out[V + row] = a1 + bb;
        }
        __syncthreads();
        buf ^= 1;
    }
}

extern "C" void kernel_launch(void* const* d_in, const int* in_sizes, int n_in,
                              void* d_out, int out_size, void* d_ws, size_t ws_size,
                              hipStream_t stream) {
    const int*   ids    = (const int*)  d_in[0];
    const float* lctx   = (const float*)d_in[1];
    const float* lhid   = (const float*)d_in[2];
    const float* enc    = (const float*)d_in[3];
    const float* emb    = (const float*)d_in[4];
    const float* w_ih   = (const float*)d_in[5];
    const float* w_hh   = (const float*)d_in[6];
    const float* b_ih   = (const float*)d_in[7];
    const float* b_hh   = (const float*)d_in[8];
    const float* attn_w = (const float*)d_in[9];
    // d_in[10] = attn_b  (unused: shift-invariant under softmax)
    const float* v      = (const float*)d_in[11];
    const float* out_w  = (const float*)d_in[12];
    const float* out_b  = (const float*)d_in[13];

    float* out_f       = (float*)d_out;
    float* o_output    = out_f;             // (2,1,50000) = 100000
    float* o_context   = out_f + 100000;    // (2,1,1024)  = 2048
    float* o_hidden    = out_f + 102048;    // (1,2,1024)  = 2048
    float* o_embedded  = out_f + 104096;    // (2,1,1024)  = 2048
    float* o_rnn       = out_f + 106144;    // (2,1,1024)  = 2048

    float* ws   = (float*)d_ws;
    float* U    = ws;                    // 1024
    float* MARR = ws + 1024;             // 2048
    float* SARR = ws + 3072;             // 2048
    float* PVEC = ws + 5120;             // 2048*1024 (~8.4 MB total)

    k_u   <<<64,   256, 0, stream>>>(attn_w, v, U);
    k_fuse<<<3080, 256, 0, stream>>>(enc, U, PVEC, MARR, SARR,
                                     ids, emb, lctx, lhid, w_ih, w_hh,
                                     b_ih, b_hh, o_hidden, o_rnn, o_embedded);
    k_red <<<64,   256, 0, stream>>>(PVEC, MARR, SARR, o_context);
    k_out <<<NBO,  256, 0, stream>>>(out_w, out_b, o_hidden, o_context,
                                     o_output);
}

// Round 13
// 108.432 us; speedup vs baseline: 1.0270x; 1.0270x over previous
//
#include <hip/hip_runtime.h>

#define H 1024
#define LEN 8192
#define V 50000
#define NTILE 12500   // k_out: V/4 rows per tile
#define NBO 500       // k_out blocks: 12500/500 = exactly 25 tiles each
#define CHUNK 8
#define NCH (LEN / CHUNK)   // 1024 chunks per batch

__device__ __forceinline__ float dot4(float4 a, float4 b) {
    return a.x * b.x + a.y * b.y + a.z * b.z + a.w * b.w;
}

__device__ __forceinline__ void gld_lds16(const float* g, float* l) {
    __builtin_amdgcn_global_load_lds(
        (const __attribute__((address_space(1))) void*)g,
        (__attribute__((address_space(3))) void*)l, 16, 0, 0);
}

// ---------------------------------------------------------------------------
// K1: fused pre-work (R5-proven).
//   blocks 0..63    : u[h] = sum_k v[k]*attn_w[k*2048+1024+h]
//   blocks 64..71   : embedding gather
//   blocks 72..1095 : GRU cell, one block per output element hh
// ---------------------------------------------------------------------------
__global__ void k_pre(const float* __restrict__ attn_w,
                      const float* __restrict__ v,
                      float* __restrict__ u,
                      const int* __restrict__ ids,
                      const float* __restrict__ emb,
                      float* __restrict__ out_emb,
                      const float* __restrict__ lctx,
                      const float* __restrict__ lhid,
                      const float* __restrict__ w_ih,
                      const float* __restrict__ w_hh,
                      const float* __restrict__ b_ih,
                      const float* __restrict__ b_hh,
                      float* __restrict__ o_hidden,
                      float* __restrict__ o_rnn) {
    __shared__ float red[16][16];
    __shared__ float lds[3][4][4];
    int bid = blockIdx.x;
    int t   = threadIdx.x;

    if (bid < 64) {
        int kg = t >> 4;            // 0..15
        int hi = t & 15;            // 0..15
        int h  = bid * 16 + hi;
        float acc = 0.f;
#pragma unroll 8
        for (int i = 0; i < 64; ++i) {
            int k = kg * 64 + i;
            acc += v[k] * attn_w[(long)k * (2 * H) + H + h];
        }
        red[kg][hi] = acc;
        __syncthreads();
        if (t < 16) {
            float s = 0.f;
#pragma unroll
            for (int g = 0; g < 16; ++g) s += red[g][t];
            u[bid * 16 + t] = s;
        }
        return;
    }
    if (bid < 72) {
        int idx = (bid - 64) * 256 + t;    // 0..2047
        int b = idx >> 10, h = idx & 1023;
        out_emb[idx] = emb[(long)ids[b] * H + h];
        return;
    }

    // ---- GRU ----
    int hh = bid - 72;            // 0..1023
    int kb = t * 8;               // x index base (0..2040)

    float4 x0a, x0b, x1a, x1b;
    if (kb < H) {
        const float* p0 = emb + (long)ids[0] * H + kb;
        const float* p1 = emb + (long)ids[1] * H + kb;
        x0a = *(const float4*)p0;  x0b = *(const float4*)(p0 + 4);
        x1a = *(const float4*)p1;  x1b = *(const float4*)(p1 + 4);
    } else {
        const float* p0 = lctx + (kb - H);
        const float* p1 = lctx + H + (kb - H);
        x0a = *(const float4*)p0;  x0b = *(const float4*)(p0 + 4);
        x1a = *(const float4*)p1;  x1b = *(const float4*)(p1 + 4);
    }
    int kb2 = t * 4;              // h index base (0..1020)
    float4 h0 = *(const float4*)(lhid + kb2);
    float4 h1 = *(const float4*)(lhid + H + kb2);

    for (int g = 0; g < 3; ++g) {
        const float* wi = w_ih + ((long)g * H + hh) * (2 * H) + kb;
        const float* wh = w_hh + ((long)g * H + hh) * H + kb2;
        float4 wa = *(const float4*)wi;
        float4 wb = *(const float4*)(wi + 4);
        float4 wc = *(const float4*)wh;
        float a0 = dot4(wa, x0a) + dot4(wb, x0b);
        float a1 = dot4(wa, x1a) + dot4(wb, x1b);
        float c0 = dot4(wc, h0);
        float c1 = dot4(wc, h1);
        for (int off = 32; off; off >>= 1) {
            a0 += __shfl_down(a0, off, 64);
            a1 += __shfl_down(a1, off, 64);
            c0 += __shfl_down(c0, off, 64);
            c1 += __shfl_down(c1, off, 64);
        }
        if ((t & 63) == 0) {
            int w = t >> 6;
            lds[g][w][0] = a0; lds[g][w][1] = a1;
            lds[g][w][2] = c0; lds[g][w][3] = c1;
        }
    }
    __syncthreads();
    if (t == 0) {
        float gx[3][2], gh[3][2];
        for (int g = 0; g < 3; ++g) {
            float s0 = 0, s1 = 0, s2 = 0, s3 = 0;
            for (int w = 0; w < 4; ++w) {
                s0 += lds[g][w][0]; s1 += lds[g][w][1];
                s2 += lds[g][w][2]; s3 += lds[g][w][3];
            }
            float bi = b_ih[g * H + hh], bh = b_hh[g * H + hh];
            gx[g][0] = s0 + bi; gx[g][1] = s1 + bi;
            gh[g][0] = s2 + bh; gh[g][1] = s3 + bh;
        }
        for (int b = 0; b < 2; ++b) {
            float r  = 1.f / (1.f + expf(-(gx[0][b] + gh[0][b])));
            float z  = 1.f / (1.f + expf(-(gx[1][b] + gh[1][b])));
            float n  = tanhf(gx[2][b] + r * gh[2][b]);
            float hp = lhid[b * H + hh];
            float hn = (1.f - z) * n + z * hp;
            o_hidden[b * H + hh] = hn;
            o_rnn[b * H + hh]    = hn;
        }
    }
}

// ---------------------------------------------------------------------------
// K2: flash-style context partials (R5-proven). Block = chunk of 8 l's.
// grid 2048 x 256
// ---------------------------------------------------------------------------
__global__ void __launch_bounds__(256)
k_ctx(const float* __restrict__ enc,
      const float* __restrict__ u,
      float* __restrict__ pvec,
      float* __restrict__ marr,
      float* __restrict__ sarr) {
    __shared__ float erow[CHUNK * H];    // 32 KB
    __shared__ float elds[CHUNK];
    int t    = threadIdx.x;
    int lane = t & 63;
    int wv   = t >> 6;
    int b    = blockIdx.x >> 10;         // 0..1
    int ch   = blockIdx.x & 1023;        // 0..1023

    const float* src = enc + ((long)b * LEN + (long)ch * CHUNK) * H;
#pragma unroll
    for (int i = 0; i < CHUNK; ++i)
        gld_lds16(src + i * H + t * 4, erow + i * H + t * 4);

    float4 uf[4];
#pragma unroll
    for (int c = 0; c < 4; ++c)
        uf[c] = *(const float4*)(u + c * 256 + lane * 4);

    __syncthreads();   // staging drained

#pragma unroll
    for (int rr = 0; rr < 2; ++rr) {
        int r = wv * 2 + rr;
        float acc = 0.f;
#pragma unroll
        for (int c = 0; c < 4; ++c) {
            float4 ev = *(const float4*)(erow + r * H + c * 256 + lane * 4);
            acc += dot4(ev, uf[c]);
        }
        for (int off = 32; off; off >>= 1) acc += __shfl_down(acc, off, 64);
        if (lane == 0) elds[r] = acc;
    }
    __syncthreads();

    float m = elds[0];
#pragma unroll
    for (int r = 1; r < CHUNK; ++r) m = fmaxf(m, elds[r]);
    float p[CHUNK];
    float s = 0.f;
#pragma unroll
    for (int r = 0; r < CHUNK; ++r) { p[r] = expf(elds[r] - m); s += p[r]; }

    float4 acc = {0.f, 0.f, 0.f, 0.f};
#pragma unroll
    for (int r = 0; r < CHUNK; ++r) {
        float4 ev = *(const float4*)(erow + r * H + t * 4);
        acc.x += p[r] * ev.x; acc.y += p[r] * ev.y;
        acc.z += p[r] * ev.z; acc.w += p[r] * ev.w;
    }
    *(float4*)(pvec + (long)blockIdx.x * H + t * 4) = acc;
    if (t == 0) { marr[blockIdx.x] = m; sarr[blockIdx.x] = s; }
}

// ---------------------------------------------------------------------------
// K3: flash combine — vectorized (R11-proven). 64 blocks; block = (b, 32 h's).
// ---------------------------------------------------------------------------
__global__ void __launch_bounds__(256)
k_red(const float* __restrict__ pvec,
      const float* __restrict__ marr,
      const float* __restrict__ sarr,
      float* __restrict__ out_ctx) {
    __shared__ float scale[NCH];        // 4 KB
    __shared__ float rbuf[4];
    __shared__ float4 part[32][8];      // 4 KB
    int t  = threadIdx.x;
    int b  = blockIdx.x >> 5;           // 0..1
    int h0 = (blockIdx.x & 31) * 32;
    const float* mb = marr + b * NCH;
    const float* sb = sarr + b * NCH;

    float m = -3.4e38f;
    for (int i = t; i < NCH; i += 256) m = fmaxf(m, mb[i]);
    for (int off = 32; off; off >>= 1) m = fmaxf(m, __shfl_xor(m, off, 64));
    if ((t & 63) == 0) rbuf[t >> 6] = m;
    __syncthreads();
    m = fmaxf(fmaxf(rbuf[0], rbuf[1]), fmaxf(rbuf[2], rbuf[3]));
    __syncthreads();

    float d = 0.f;
    for (int i = t; i < NCH; i += 256) {
        float sc = expf(mb[i] - m);
        scale[i] = sc;
        d += sc * sb[i];
    }
    for (int off = 32; off; off >>= 1) d += __shfl_xor(d, off, 64);
    if ((t & 63) == 0) rbuf[t >> 6] = d;
    __syncthreads();
    float inv = 1.f / (rbuf[0] + rbuf[1] + rbuf[2] + rbuf[3]);

    // weighted sum: hq = float4-slice of the 32 h's; clane = chunk lane
    int hq    = t & 7;                  // 0..7
    int clane = t >> 3;                 // 0..31
    const float* pv = pvec + (long)b * NCH * H + h0 + hq * 4;
    float4 acc = {0.f, 0.f, 0.f, 0.f};
#pragma unroll
    for (int k = 0; k < 32; ++k) {
        int c = clane + 32 * k;
        float sc = scale[c];
        float4 p = *(const float4*)(pv + (long)c * H);
        acc.x += sc * p.x; acc.y += sc * p.y;
        acc.z += sc * p.z; acc.w += sc * p.w;
    }
    part[clane][hq] = acc;
    __syncthreads();
    if (t < 8) {
        float4 s4 = {0.f, 0.f, 0.f, 0.f};
#pragma unroll
        for (int c = 0; c < 32; ++c) {
            float4 p = part[c][t];
            s4.x += p.x; s4.y += p.y; s4.z += p.z; s4.w += p.w;
        }
        s4.x *= inv; s4.y *= inv; s4.z *= inv; s4.w *= inv;
        *(float4*)(out_ctx + b * H + h0 + t * 4) = s4;
    }
}

// ---------------------------------------------------------------------------
// K4: output projection (R11-proven). grid 500 x 256 -> exactly 25 tiles
// per block, uniform finish.
// ---------------------------------------------------------------------------
__global__ void __launch_bounds__(256)
k_out(const float* __restrict__ ow,
      const float* __restrict__ ob,
      const float* __restrict__ hnew,
      const float* __restrict__ ctx,
      float* __restrict__ out) {
    __shared__ float cat[2][2 * H];       // 16 KB
    __shared__ float wt[2][4 * 2 * H];    // 64 KB
    int t    = threadIdx.x;
    int lane = t & 63;
    int wv   = t >> 6;

    {
        float4* c0 = (float4*)cat[0];
        float4* c1 = (float4*)cat[1];
#pragma unroll
        for (int r = 0; r < 2; ++r) {
            int idx = t + r * 256;
            int k   = idx * 4;
            if (k < H) {
                c0[idx] = *(const float4*)(hnew + k);
                c1[idx] = *(const float4*)(hnew + H + k);
            } else {
                c0[idx] = *(const float4*)(ctx + (k - H));
                c1[idx] = *(const float4*)(ctx + H + (k - H));
            }
        }
    }
    {
        const float* src = ow + (long)blockIdx.x * (4 * 2 * H);
#pragma unroll
        for (int i = 0; i < 8; ++i)
            gld_lds16(src + i * 1024 + t * 4, wt[0] + i * 1024 + t * 4);
    }
    __syncthreads();

    const float4* c0 = (const float4*)cat[0];
    const float4* c1 = (const float4*)cat[1];
    int buf = 0;
    for (int T = blockIdx.x; T < NTILE; T += NBO) {
        int Tn = T + NBO;
        if (Tn < NTILE) {
            const float* src = ow + (long)Tn * (4 * 2 * H);
            float* dst = wt[buf ^ 1];
#pragma unroll
            for (int i = 0; i < 8; ++i)
                gld_lds16(src + i * 1024 + t * 4, dst + i * 1024 + t * 4);
        }
        const float4* wr = (const float4*)(wt[buf] + wv * (2 * H));
        float a0 = 0.f, a1 = 0.f;
#pragma unroll
        for (int j = 0; j < 8; ++j) {
            float4 w = wr[lane + 64 * j];
            a0 += dot4(w, c0[lane + 64 * j]);
            a1 += dot4(w, c1[lane + 64 * j]);
        }
        for (int off = 32; off; off >>= 1) {
            a0 += __shfl_down(a0, off, 64);
            a1 += __shfl_down(a1, off, 64);
        }
        if (lane == 0) {
            long row = (long)T * 4 + wv;
            float bb = ob[row];
            out[row]     = a0 + bb;
            out[V + row] = a1 + bb;
        }
        __syncthreads();
        buf ^= 1;
    }
}

extern "C" void kernel_launch(void* const* d_in, const int* in_sizes, int n_in,
                              void* d_out, int out_size, void* d_ws, size_t ws_size,
                              hipStream_t stream) {
    const int*   ids    = (const int*)  d_in[0];
    const float* lctx   = (const float*)d_in[1];
    const float* lhid   = (const float*)d_in[2];
    const float* enc    = (const float*)d_in[3];
    const float* emb    = (const float*)d_in[4];
    const float* w_ih   = (const float*)d_in[5];
    const float* w_hh   = (const float*)d_in[6];
    const float* b_ih   = (const float*)d_in[7];
    const float* b_hh   = (const float*)d_in[8];
    const float* attn_w = (const float*)d_in[9];
    // d_in[10] = attn_b  (unused: shift-invariant under softmax)
    const float* v      = (const float*)d_in[11];
    const float* out_w  = (const float*)d_in[12];
    const float* out_b  = (const float*)d_in[13];

    float* out_f       = (float*)d_out;
    float* o_output    = out_f;             // (2,1,50000) = 100000
    float* o_context   = out_f + 100000;    // (2,1,1024)  = 2048
    float* o_hidden    = out_f + 102048;    // (1,2,1024)  = 2048
    float* o_embedded  = out_f + 104096;    // (2,1,1024)  = 2048
    float* o_rnn       = out_f + 106144;    // (2,1,1024)  = 2048

    float* ws   = (float*)d_ws;
    float* U    = ws;                    // 1024
    float* MARR = ws + 1024;             // 2048
    float* SARR = ws + 3072;             // 2048
    float* PVEC = ws + 5120;             // 2048*1024 (~8.4 MB total)

    k_pre<<<1096, 256, 0, stream>>>(attn_w, v, U, ids, emb, o_embedded,
                                    lctx, lhid, w_ih, w_hh, b_ih, b_hh,
                                    o_hidden, o_rnn);
    k_ctx<<<2048, 256, 0, stream>>>(enc, U, PVEC, MARR, SARR);
    k_red<<<64,   256, 0, stream>>>(PVEC, MARR, SARR, o_context);
    k_out<<<NBO,  256, 0, stream>>>(out_w, out_b, o_hidden, o_context,
                                    o_output);
}